// Round 2
// baseline (477.243 us; speedup 1.0000x reference)
//
#include <hip/hip_runtime.h>
#include <hip/hip_bf16.h>

typedef unsigned short u16;
typedef unsigned int u32;
typedef __attribute__((ext_vector_type(8))) short short8;
typedef __attribute__((ext_vector_type(4))) float floatx4;

#define NPIX 12544   // 112*112 = 49 * 256
#define KDIM 768     // channels = 12 * 64
#define EPSF 1e-8f
#define NT 12        // K tiles of 64
#define NTILE 49     // 12544 / 256

// ---------------------------------------------------------------- async G->LDS
__device__ __forceinline__ void gload_lds16(const void* g, void* l) {
  __builtin_amdgcn_global_load_lds(
      (const __attribute__((address_space(1))) void*)g,
      (__attribute__((address_space(3))) void*)l, 16, 0, 0);
}

// sortable-uint encoding of float (monotone): max over enc == max over float
__device__ __forceinline__ u32 enc_f32(float f) {
  u32 u = __float_as_uint(f);
  return (u & 0x80000000u) ? ~u : (u | 0x80000000u);
}
__device__ __forceinline__ float dec_f32(u32 e) {
  u32 u = (e & 0x80000000u) ? (e & 0x7FFFFFFFu) : ~e;
  return __uint_as_float(u);
}

// ---------------------------------------------------------------- K1: column sum-of-squares partials
// grid (49, 8), block 256. pa/pb: [8][NPIX]
__global__ void colsumsq_kernel(const float* __restrict__ a, const float* __restrict__ b,
                                float* __restrict__ pa, float* __restrict__ pb) {
  int i = blockIdx.x * 256 + threadIdx.x;
  int c0 = blockIdx.y * 96;
  float sa = 0.f, sb = 0.f;
#pragma unroll 4
  for (int c = c0; c < c0 + 96; ++c) {
    float va = a[(size_t)c * NPIX + i];
    float vb = b[(size_t)c * NPIX + i];
    sa += va * va;
    sb += vb * vb;
  }
  pa[(size_t)blockIdx.y * NPIX + i] = sa;
  pb[(size_t)blockIdx.y * NPIX + i] = sb;
}

// ---------------------------------------------------------------- K2: 1/(sqrt(sum+eps)+eps) + zero the atomic-max buffer
// grid 49, block 256
__global__ void rnorm_kernel(const float* __restrict__ pa, const float* __restrict__ pb,
                             float* __restrict__ ra, float* __restrict__ rb,
                             u32* __restrict__ part) {
  int i = blockIdx.x * 256 + threadIdx.x;
  float sa = 0.f, sb = 0.f;
#pragma unroll
  for (int c = 0; c < 8; ++c) {
    sa += pa[(size_t)c * NPIX + i];
    sb += pb[(size_t)c * NPIX + i];
  }
  ra[i] = 1.f / (sqrtf(sa + EPSF) + EPSF);
  rb[i] = 1.f / (sqrtf(sb + EPSF) + EPSF);
  part[i] = 0u;  // encoded floor (< enc of any finite float)
}

// ---------------------------------------------------------------- K3: transpose + normalize + bf16 cast
// (C,N) f32 -> (N,C) bf16.  grid (392, 24, 2), block 256 (=32x8)
__global__ void transpose_kernel(const float* __restrict__ a, const float* __restrict__ b,
                                 const float* __restrict__ ra, const float* __restrict__ rb,
                                 u16* __restrict__ Ar, u16* __restrict__ Br) {
  const float* src = blockIdx.z ? b : a;
  const float* rn  = blockIdx.z ? rb : ra;
  u16* dst         = blockIdx.z ? Br : Ar;
  __shared__ float tile[32][33];
  int i0 = blockIdx.x * 32;
  int c0 = blockIdx.y * 32;
  int tx = threadIdx.x & 31;
  int ty = threadIdx.x >> 5;  // 0..7
#pragma unroll
  for (int d = 0; d < 4; ++d) {
    int c = c0 + ty + d * 8;
    tile[ty + d * 8][tx] = src[(size_t)c * NPIX + i0 + tx];
  }
  __syncthreads();
#pragma unroll
  for (int d = 0; d < 4; ++d) {
    int il = ty + d * 8;
    int gi = i0 + il;
    float v = tile[tx][il] * rn[gi];
    __hip_bfloat16 h = __float2bfloat16(v);
    dst[(size_t)gi * KDIM + c0 + tx] = *reinterpret_cast<u16*>(&h);
  }
}

// ---------------------------------------------------------------- K4: 256x256 tile, 8 waves, BK=64,
// 4-phase interleaved schedule with counted-lead staging (T2+T3+T4+T5), row-max atomic epilogue.
// LDS: A,B double-buffered = 2buf x 2half x 128x64 bf16 x {A,B} = 128 KiB.
// Per wave (wm=wid>>2, wn=wid&3): output 128 rows x 64 cols = acc[8][4] 16x16 frags.
// Phases per K-tile (each: ds_reads + stage -> bar -> lgkmcnt(0) -> prio1 -> 16 MFMA -> prio0 -> bar):
//   P0: A(m0-3,kk0)+B(n0-3,kk0) reads (8), stage next-tile A halves (4 gloads)
//   P1: A(m4-7,kk0) reads (4),            stage next-tile B halves (4 gloads)
//   P2: A(m0-3,kk1)+B(n0-3,kk1) reads (8)
//   P3: A(m4-7,kk1) reads (4), vmcnt(0) AFTER P3 MFMA (loads had ~3 phases of cover)
// LDS swizzle: row r, logical 16B-chunk c stored at slot (c + r) & 7; global source is
// pre-swizzled so global_load_lds dest stays linear (both-sides-or-neither).
__global__ __launch_bounds__(512, 2) void gemm_max_kernel(const u16* __restrict__ Ar,
                                                          const u16* __restrict__ Br,
                                                          u32* __restrict__ part) {
  // bijective XCD swizzle (nwg = 2401 = 8*300 + 1): consecutive wgid (same B panel) on one XCD
  const int nwg = NTILE * NTILE;
  const int qq = nwg >> 3, rmv = nwg & 7;
  const int xcd = blockIdx.x & 7, idx = blockIdx.x >> 3;
  const int wgid = (xcd < rmv ? xcd * (qq + 1) : rmv * (qq + 1) + (xcd - rmv) * qq) + idx;
  const int ct = wgid / NTILE;
  const int rt = wgid - ct * NTILE;
  const int row_base = rt * 256;
  const int col_base = ct * 256;

  __shared__ alignas(16) u16 As[2][2][128 * 64];  // [buf][half][row*64 + slot*8]
  __shared__ alignas(16) u16 Bs[2][2][128 * 64];

  const int tid = threadIdx.x;
  const int lane = tid & 63;
  const int wid = tid >> 6;   // 0..7
  const int wm = wid >> 2;    // A half (0..1)
  const int wn = wid & 3;     // B quarter (0..3)
  const int l15 = lane & 15;
  const int quad = lane >> 4;
  const int rb0 = (wn & 1) * 64;  // B row base within half (wn>>1)

  // staging: thread covers (row tid>>3 [+64], slot tid&7). Source chunk pre-swizzled:
  // LDS (row r, slot s) must hold logical chunk (s - r) & 7  (64 = 0 mod 8, so same for j=1)
  const int srow = tid >> 3;
  const int clog = ((tid & 7) - srow) & 7;
  const u16* gA = Ar + (size_t)(row_base + srow) * KDIM + clog * 8;
  const u16* gB = Br + (size_t)(col_base + srow) * KDIM + clog * 8;

  auto stageA = [&](int buf, int h, int t) {
    const u16* g = gA + (size_t)(h * 128) * KDIM + t * 64;
    gload_lds16(g, &As[buf][h][tid * 8]);
    gload_lds16(g + (size_t)64 * KDIM, &As[buf][h][4096 + tid * 8]);
  };
  auto stageB = [&](int buf, int h, int t) {
    const u16* g = gB + (size_t)(h * 128) * KDIM + t * 64;
    gload_lds16(g, &Bs[buf][h][tid * 8]);
    gload_lds16(g + (size_t)64 * KDIM, &Bs[buf][h][4096 + tid * 8]);
  };
  // frag read address (elements): row-major 64/row, slot rotated by row
  auto swz = [&](int row, int kk) {
    return row * 64 + ((((kk << 2) + quad + row) & 7) << 3);
  };

  floatx4 acc[8][4];
#pragma unroll
  for (int m = 0; m < 8; ++m)
#pragma unroll
    for (int n = 0; n < 4; ++n) acc[m][n] = (floatx4){0.f, 0.f, 0.f, 0.f};

  // prologue: tile 0 into buf 0
  stageA(0, 0, 0); stageA(0, 1, 0); stageB(0, 0, 0); stageB(0, 1, 0);
  asm volatile("s_waitcnt vmcnt(0)" ::: "memory");
  __builtin_amdgcn_s_barrier();

  for (int t = 0; t < NT; ++t) {
    const int buf = t & 1;
    const u16* pA = &As[buf][wm][0];
    const u16* pB = &Bs[buf][wn >> 1][0];
    const bool pf = (t + 1 < NT);
    short8 a_frag[4], b_frag[4];

    // ---------------- P0: kk0, m0-3 x n0-3
#pragma unroll
    for (int mm = 0; mm < 4; ++mm)
      a_frag[mm] = *(const short8*)&pA[swz(mm * 16 + l15, 0)];
#pragma unroll
    for (int n = 0; n < 4; ++n)
      b_frag[n] = *(const short8*)&pB[swz(rb0 + n * 16 + l15, 0)];
    if (pf) { stageA(buf ^ 1, 0, t + 1); stageA(buf ^ 1, 1, t + 1); }
    __builtin_amdgcn_s_barrier();
    asm volatile("s_waitcnt lgkmcnt(0)" ::: "memory");
    __builtin_amdgcn_sched_barrier(0);
    __builtin_amdgcn_s_setprio(1);
#pragma unroll
    for (int mm = 0; mm < 4; ++mm)
#pragma unroll
      for (int n = 0; n < 4; ++n)
        acc[mm][n] = __builtin_amdgcn_mfma_f32_16x16x32_bf16(a_frag[mm], b_frag[n], acc[mm][n], 0, 0, 0);
    __builtin_amdgcn_s_setprio(0);
    __builtin_amdgcn_s_barrier();

    // ---------------- P1: kk0, m4-7 x n0-3 (B frags reused from regs)
#pragma unroll
    for (int mm = 0; mm < 4; ++mm)
      a_frag[mm] = *(const short8*)&pA[swz((mm + 4) * 16 + l15, 0)];
    if (pf) { stageB(buf ^ 1, 0, t + 1); stageB(buf ^ 1, 1, t + 1); }
    __builtin_amdgcn_s_barrier();
    asm volatile("s_waitcnt lgkmcnt(0)" ::: "memory");
    __builtin_amdgcn_sched_barrier(0);
    __builtin_amdgcn_s_setprio(1);
#pragma unroll
    for (int mm = 0; mm < 4; ++mm)
#pragma unroll
      for (int n = 0; n < 4; ++n)
        acc[mm + 4][n] = __builtin_amdgcn_mfma_f32_16x16x32_bf16(a_frag[mm], b_frag[n], acc[mm + 4][n], 0, 0, 0);
    __builtin_amdgcn_s_setprio(0);
    __builtin_amdgcn_s_barrier();

    // ---------------- P2: kk1, m0-3 x n0-3
#pragma unroll
    for (int mm = 0; mm < 4; ++mm)
      a_frag[mm] = *(const short8*)&pA[swz(mm * 16 + l15, 1)];
#pragma unroll
    for (int n = 0; n < 4; ++n)
      b_frag[n] = *(const short8*)&pB[swz(rb0 + n * 16 + l15, 1)];
    __builtin_amdgcn_s_barrier();
    asm volatile("s_waitcnt lgkmcnt(0)" ::: "memory");
    __builtin_amdgcn_sched_barrier(0);
    __builtin_amdgcn_s_setprio(1);
#pragma unroll
    for (int mm = 0; mm < 4; ++mm)
#pragma unroll
      for (int n = 0; n < 4; ++n)
        acc[mm][n] = __builtin_amdgcn_mfma_f32_16x16x32_bf16(a_frag[mm], b_frag[n], acc[mm][n], 0, 0, 0);
    __builtin_amdgcn_s_setprio(0);
    __builtin_amdgcn_s_barrier();

    // ---------------- P3: kk1, m4-7 x n0-3; vmcnt drain at tile boundary
#pragma unroll
    for (int mm = 0; mm < 4; ++mm)
      a_frag[mm] = *(const short8*)&pA[swz((mm + 4) * 16 + l15, 1)];
    __builtin_amdgcn_s_barrier();
    asm volatile("s_waitcnt lgkmcnt(0)" ::: "memory");
    __builtin_amdgcn_sched_barrier(0);
    __builtin_amdgcn_s_setprio(1);
#pragma unroll
    for (int mm = 0; mm < 4; ++mm)
#pragma unroll
      for (int n = 0; n < 4; ++n)
        acc[mm + 4][n] = __builtin_amdgcn_mfma_f32_16x16x32_bf16(a_frag[mm], b_frag[n], acc[mm + 4][n], 0, 0, 0);
    __builtin_amdgcn_s_setprio(0);
    asm volatile("s_waitcnt vmcnt(0)" ::: "memory");
    __builtin_amdgcn_s_barrier();
  }

  // epilogue: per-row max over the 256-col tile.
  // C frag layout: col = l15 (+n*16), row = quad*4 + rr (+m*16, +wm*128)
  float* s_max = reinterpret_cast<float*>(&As[0][0][0]);  // [4][256], overlays As (done with LDS)
#pragma unroll
  for (int m = 0; m < 8; ++m) {
#pragma unroll
    for (int rr = 0; rr < 4; ++rr) {
      float best = fmaxf(fmaxf(acc[m][0][rr], acc[m][1][rr]),
                         fmaxf(acc[m][2][rr], acc[m][3][rr]));
      best = fmaxf(best, __shfl_xor(best, 1));
      best = fmaxf(best, __shfl_xor(best, 2));
      best = fmaxf(best, __shfl_xor(best, 4));
      best = fmaxf(best, __shfl_xor(best, 8));
      if (l15 == 0)
        s_max[wn * 256 + wm * 128 + m * 16 + quad * 4 + rr] = best;  // unique writer per entry
    }
  }
  __syncthreads();
  if (tid < 256) {
    float mx = fmaxf(fmaxf(s_max[tid], s_max[256 + tid]),
                     fmaxf(s_max[512 + tid], s_max[768 + tid]));
    atomicMax(&part[row_base + tid], enc_f32(mx));
  }
}

// ---------------------------------------------------------------- K5: decode + loss
// single block, 1024 threads; output fp32 scalar
__global__ void finish_kernel(const u32* __restrict__ part, float* __restrict__ out) {
  float v = 0.f;
  for (int i = threadIdx.x; i < NPIX; i += 1024) {
    v += 1.0f - dec_f32(part[i]);
  }
#pragma unroll
  for (int off = 32; off > 0; off >>= 1) v += __shfl_down(v, off);
  __shared__ float red[16];
  int w = threadIdx.x >> 6;
  if ((threadIdx.x & 63) == 0) red[w] = v;
  __syncthreads();
  if (threadIdx.x == 0) {
    float s = 0.f;
#pragma unroll
    for (int k = 0; k < 16; ++k) s += red[k];
    out[0] = s * (1.0f / (float)NPIX);
  }
}

// ---------------------------------------------------------------- launcher
extern "C" void kernel_launch(void* const* d_in, const int* in_sizes, int n_in,
                              void* d_out, int out_size, void* d_ws, size_t ws_size,
                              hipStream_t stream) {
  const float* x = (const float*)d_in[0];
  const float* s = (const float*)d_in[1];
  char* ws = (char*)d_ws;
  // layout (bytes):
  float* pa   = (float*)(ws + 0);         //   401408
  float* pb   = (float*)(ws + 401408);    //   401408
  float* ra   = (float*)(ws + 802816);    //    50176
  float* rb   = (float*)(ws + 852992);    //    50176
  u32*   part = (u32*)  (ws + 903168);    //    50176 (encoded row maxima)
  u16*   Ar   = (u16*)  (ws + 953344);    // 19267584
  u16*   Br   = (u16*)  (ws + 20220928);  // 19267584  -> total 39488512 B

  colsumsq_kernel<<<dim3(49, 8), 256, 0, stream>>>(x, s, pa, pb);
  rnorm_kernel<<<49, 256, 0, stream>>>(pa, pb, ra, rb, part);
  transpose_kernel<<<dim3(392, 24, 2), 256, 0, stream>>>(x, s, ra, rb, Ar, Br);
  gemm_max_kernel<<<NTILE * NTILE, 512, 0, stream>>>(Ar, Br, part);
  finish_kernel<<<1, 1024, 0, stream>>>(part, (float*)d_out);
}

// Round 3
// 459.343 us; speedup vs baseline: 1.0390x; 1.0390x over previous
//
#include <hip/hip_runtime.h>
#include <hip/hip_bf16.h>

typedef unsigned short u16;
typedef unsigned int u32;
typedef __attribute__((ext_vector_type(8))) short short8;
typedef __attribute__((ext_vector_type(4))) float floatx4;

#define NPIX 12544   // 112*112 = 49 * 256
#define KDIM 768     // channels = 12 * 64
#define EPSF 1e-8f
#define NT 12        // K tiles of 64
#define NTILE 49     // 12544 / 256

// ---------------------------------------------------------------- async G->LDS
__device__ __forceinline__ void gload_lds16(const void* g, void* l) {
  __builtin_amdgcn_global_load_lds(
      (const __attribute__((address_space(1))) void*)g,
      (__attribute__((address_space(3))) void*)l, 16, 0, 0);
}

// sortable-uint encoding of float (monotone): max over enc == max over float
__device__ __forceinline__ u32 enc_f32(float f) {
  u32 u = __float_as_uint(f);
  return (u & 0x80000000u) ? ~u : (u | 0x80000000u);
}
__device__ __forceinline__ float dec_f32(u32 e) {
  u32 u = (e & 0x80000000u) ? (e & 0x7FFFFFFFu) : ~e;
  return __uint_as_float(u);
}

// ---------------------------------------------------------------- K1: column sum-of-squares partials
// grid (49, 8), block 256. pa/pb: [8][NPIX]
__global__ void colsumsq_kernel(const float* __restrict__ a, const float* __restrict__ b,
                                float* __restrict__ pa, float* __restrict__ pb) {
  int i = blockIdx.x * 256 + threadIdx.x;
  int c0 = blockIdx.y * 96;
  float sa = 0.f, sb = 0.f;
#pragma unroll 4
  for (int c = c0; c < c0 + 96; ++c) {
    float va = a[(size_t)c * NPIX + i];
    float vb = b[(size_t)c * NPIX + i];
    sa += va * va;
    sb += vb * vb;
  }
  pa[(size_t)blockIdx.y * NPIX + i] = sa;
  pb[(size_t)blockIdx.y * NPIX + i] = sb;
}

// ---------------------------------------------------------------- K2: 1/(sqrt(sum+eps)+eps) + zero the atomic-max buffer
// grid 49, block 256
__global__ void rnorm_kernel(const float* __restrict__ pa, const float* __restrict__ pb,
                             float* __restrict__ ra, float* __restrict__ rb,
                             u32* __restrict__ part) {
  int i = blockIdx.x * 256 + threadIdx.x;
  float sa = 0.f, sb = 0.f;
#pragma unroll
  for (int c = 0; c < 8; ++c) {
    sa += pa[(size_t)c * NPIX + i];
    sb += pb[(size_t)c * NPIX + i];
  }
  ra[i] = 1.f / (sqrtf(sa + EPSF) + EPSF);
  rb[i] = 1.f / (sqrtf(sb + EPSF) + EPSF);
  part[i] = 0u;  // encoded floor (< enc of any finite float)
}

// ---------------------------------------------------------------- K3: transpose + normalize + bf16 cast
// (C,N) f32 -> (N,C) bf16.  grid (392, 24, 2), block 256 (=32x8)
__global__ void transpose_kernel(const float* __restrict__ a, const float* __restrict__ b,
                                 const float* __restrict__ ra, const float* __restrict__ rb,
                                 u16* __restrict__ Ar, u16* __restrict__ Br) {
  const float* src = blockIdx.z ? b : a;
  const float* rn  = blockIdx.z ? rb : ra;
  u16* dst         = blockIdx.z ? Br : Ar;
  __shared__ float tile[32][33];
  int i0 = blockIdx.x * 32;
  int c0 = blockIdx.y * 32;
  int tx = threadIdx.x & 31;
  int ty = threadIdx.x >> 5;  // 0..7
#pragma unroll
  for (int d = 0; d < 4; ++d) {
    int c = c0 + ty + d * 8;
    tile[ty + d * 8][tx] = src[(size_t)c * NPIX + i0 + tx];
  }
  __syncthreads();
#pragma unroll
  for (int d = 0; d < 4; ++d) {
    int il = ty + d * 8;
    int gi = i0 + il;
    float v = tile[tx][il] * rn[gi];
    __hip_bfloat16 h = __float2bfloat16(v);
    dst[(size_t)gi * KDIM + c0 + tx] = *reinterpret_cast<u16*>(&h);
  }
}

// ---------------------------------------------------------------- K4: 256x256 tile, 8 waves, BK=64,
// 4-phase interleaved schedule (T2+T3+T4+T5), row-max atomic epilogue.
// Dispatch (proven 2-D XCD scheme): grid (8, 7, 49). x = XCD (linear%8 round-robins XCDs),
// y = col tile within the XCD's chunk (XCD0: 7 tiles, XCD1-7: 6; dead y exits early),
// z = row tile SLOWEST -> A panel (384 KB) shared chip-wide per z-wave; B chunk
// (6-7 x 384 KB = 2.3-2.7 MB) pinned in the owning XCD's L2.
// LDS: A,B double-buffered = 2buf x 2half x 128x64 bf16 x {A,B} = 128 KiB.
// Per wave (wm=wid>>2, wn=wid&3): output 128 rows x 64 cols = acc[8][4] 16x16 frags.
// Phases per K-tile (each: ds_reads + stage -> bar -> lgkmcnt(0) -> prio1 -> 16 MFMA -> prio0 -> bar):
//   P0: A(m0-3,kk0)+B(n0-3,kk0) reads (8), stage next-tile A halves (4 gloads)
//   P1: A(m4-7,kk0) reads (4),            stage next-tile B halves (4 gloads)
//   P2: A(m0-3,kk1)+B(n0-3,kk1) reads (8)
//   P3: A(m4-7,kk1) reads (4), vmcnt(0) AFTER P3 MFMA (loads had 2-3 phases of cover)
// LDS swizzle: row r, logical 16B-chunk c stored at slot (c + r) & 7; global source is
// pre-swizzled so global_load_lds dest stays linear (both-sides-or-neither).
__global__ __launch_bounds__(512, 2) void gemm_max_kernel(const u16* __restrict__ Ar,
                                                          const u16* __restrict__ Br,
                                                          u32* __restrict__ part) {
  const int x = blockIdx.x;                 // XCD chunk (linear%8 == x)
  const int y = blockIdx.y;                 // col tile within chunk
  const int live = (x == 0) ? 7 : 6;
  if (y >= live) return;                    // dead padding block (exits before any barrier)
  const int ct = (x == 0) ? y : 7 + (x - 1) * 6 + y;
  const int rt = blockIdx.z;
  const int row_base = rt * 256;
  const int col_base = ct * 256;

  __shared__ alignas(16) u16 As[2][2][128 * 64];  // [buf][half][row*64 + slot*8]
  __shared__ alignas(16) u16 Bs[2][2][128 * 64];

  const int tid = threadIdx.x;
  const int lane = tid & 63;
  const int wid = tid >> 6;   // 0..7
  const int wm = wid >> 2;    // A half (0..1)
  const int wn = wid & 3;     // B quarter (0..3)
  const int l15 = lane & 15;
  const int quad = lane >> 4;
  const int rb0 = (wn & 1) * 64;  // B row base within half (wn>>1)

  // staging: thread covers (row tid>>3 [+64], slot tid&7). Source chunk pre-swizzled:
  // LDS (row r, slot s) must hold logical chunk (s - r) & 7  (64 = 0 mod 8, so same for j=1)
  const int srow = tid >> 3;
  const int clog = ((tid & 7) - srow) & 7;
  const u16* gA = Ar + (size_t)(row_base + srow) * KDIM + clog * 8;
  const u16* gB = Br + (size_t)(col_base + srow) * KDIM + clog * 8;

  auto stageA = [&](int buf, int h, int t) {
    const u16* g = gA + (size_t)(h * 128) * KDIM + t * 64;
    gload_lds16(g, &As[buf][h][tid * 8]);
    gload_lds16(g + (size_t)64 * KDIM, &As[buf][h][4096 + tid * 8]);
  };
  auto stageB = [&](int buf, int h, int t) {
    const u16* g = gB + (size_t)(h * 128) * KDIM + t * 64;
    gload_lds16(g, &Bs[buf][h][tid * 8]);
    gload_lds16(g + (size_t)64 * KDIM, &Bs[buf][h][4096 + tid * 8]);
  };
  // frag read address (elements): row-major 64/row, slot rotated by row
  auto swz = [&](int row, int kk) {
    return row * 64 + ((((kk << 2) + quad + row) & 7) << 3);
  };

  floatx4 acc[8][4];
#pragma unroll
  for (int m = 0; m < 8; ++m)
#pragma unroll
    for (int n = 0; n < 4; ++n) acc[m][n] = (floatx4){0.f, 0.f, 0.f, 0.f};

  // prologue: tile 0 into buf 0
  stageA(0, 0, 0); stageA(0, 1, 0); stageB(0, 0, 0); stageB(0, 1, 0);
  asm volatile("s_waitcnt vmcnt(0)" ::: "memory");
  __builtin_amdgcn_s_barrier();

  for (int t = 0; t < NT; ++t) {
    const int buf = t & 1;
    const u16* pA = &As[buf][wm][0];
    const u16* pB = &Bs[buf][wn >> 1][0];
    const bool pf = (t + 1 < NT);
    short8 a_frag[4], b_frag[4];

    // ---------------- P0: kk0, m0-3 x n0-3
#pragma unroll
    for (int mm = 0; mm < 4; ++mm)
      a_frag[mm] = *(const short8*)&pA[swz(mm * 16 + l15, 0)];
#pragma unroll
    for (int n = 0; n < 4; ++n)
      b_frag[n] = *(const short8*)&pB[swz(rb0 + n * 16 + l15, 0)];
    if (pf) { stageA(buf ^ 1, 0, t + 1); stageA(buf ^ 1, 1, t + 1); }
    __builtin_amdgcn_s_barrier();
    asm volatile("s_waitcnt lgkmcnt(0)" ::: "memory");
    __builtin_amdgcn_sched_barrier(0);
    __builtin_amdgcn_s_setprio(1);
#pragma unroll
    for (int mm = 0; mm < 4; ++mm)
#pragma unroll
      for (int n = 0; n < 4; ++n)
        acc[mm][n] = __builtin_amdgcn_mfma_f32_16x16x32_bf16(a_frag[mm], b_frag[n], acc[mm][n], 0, 0, 0);
    __builtin_amdgcn_s_setprio(0);
    __builtin_amdgcn_s_barrier();

    // ---------------- P1: kk0, m4-7 x n0-3 (B frags reused from regs)
#pragma unroll
    for (int mm = 0; mm < 4; ++mm)
      a_frag[mm] = *(const short8*)&pA[swz((mm + 4) * 16 + l15, 0)];
    if (pf) { stageB(buf ^ 1, 0, t + 1); stageB(buf ^ 1, 1, t + 1); }
    __builtin_amdgcn_s_barrier();
    asm volatile("s_waitcnt lgkmcnt(0)" ::: "memory");
    __builtin_amdgcn_sched_barrier(0);
    __builtin_amdgcn_s_setprio(1);
#pragma unroll
    for (int mm = 0; mm < 4; ++mm)
#pragma unroll
      for (int n = 0; n < 4; ++n)
        acc[mm + 4][n] = __builtin_amdgcn_mfma_f32_16x16x32_bf16(a_frag[mm], b_frag[n], acc[mm + 4][n], 0, 0, 0);
    __builtin_amdgcn_s_setprio(0);
    __builtin_amdgcn_s_barrier();

    // ---------------- P2: kk1, m0-3 x n0-3
#pragma unroll
    for (int mm = 0; mm < 4; ++mm)
      a_frag[mm] = *(const short8*)&pA[swz(mm * 16 + l15, 1)];
#pragma unroll
    for (int n = 0; n < 4; ++n)
      b_frag[n] = *(const short8*)&pB[swz(rb0 + n * 16 + l15, 1)];
    __builtin_amdgcn_s_barrier();
    asm volatile("s_waitcnt lgkmcnt(0)" ::: "memory");
    __builtin_amdgcn_sched_barrier(0);
    __builtin_amdgcn_s_setprio(1);
#pragma unroll
    for (int mm = 0; mm < 4; ++mm)
#pragma unroll
      for (int n = 0; n < 4; ++n)
        acc[mm][n] = __builtin_amdgcn_mfma_f32_16x16x32_bf16(a_frag[mm], b_frag[n], acc[mm][n], 0, 0, 0);
    __builtin_amdgcn_s_setprio(0);
    __builtin_amdgcn_s_barrier();

    // ---------------- P3: kk1, m4-7 x n0-3; vmcnt drain at tile boundary
#pragma unroll
    for (int mm = 0; mm < 4; ++mm)
      a_frag[mm] = *(const short8*)&pA[swz((mm + 4) * 16 + l15, 1)];
    __builtin_amdgcn_s_barrier();
    asm volatile("s_waitcnt lgkmcnt(0)" ::: "memory");
    __builtin_amdgcn_sched_barrier(0);
    __builtin_amdgcn_s_setprio(1);
#pragma unroll
    for (int mm = 0; mm < 4; ++mm)
#pragma unroll
      for (int n = 0; n < 4; ++n)
        acc[mm + 4][n] = __builtin_amdgcn_mfma_f32_16x16x32_bf16(a_frag[mm], b_frag[n], acc[mm + 4][n], 0, 0, 0);
    __builtin_amdgcn_s_setprio(0);
    asm volatile("s_waitcnt vmcnt(0)" ::: "memory");
    __builtin_amdgcn_s_barrier();
  }

  // epilogue: per-row max over the 256-col tile.
  // C frag layout: col = l15 (+n*16), row = quad*4 + rr (+m*16, +wm*128)
  float* s_max = reinterpret_cast<float*>(&As[0][0][0]);  // [4][256], overlays As (done with LDS)
#pragma unroll
  for (int m = 0; m < 8; ++m) {
#pragma unroll
    for (int rr = 0; rr < 4; ++rr) {
      float best = fmaxf(fmaxf(acc[m][0][rr], acc[m][1][rr]),
                         fmaxf(acc[m][2][rr], acc[m][3][rr]));
      best = fmaxf(best, __shfl_xor(best, 1));
      best = fmaxf(best, __shfl_xor(best, 2));
      best = fmaxf(best, __shfl_xor(best, 4));
      best = fmaxf(best, __shfl_xor(best, 8));
      if (l15 == 0)
        s_max[wn * 256 + wm * 128 + m * 16 + quad * 4 + rr] = best;  // unique writer per entry
    }
  }
  __syncthreads();
  if (tid < 256) {
    float mx = fmaxf(fmaxf(s_max[tid], s_max[256 + tid]),
                     fmaxf(s_max[512 + tid], s_max[768 + tid]));
    atomicMax(&part[row_base + tid], enc_f32(mx));
  }
}

// ---------------------------------------------------------------- K5: decode + loss
// single block, 1024 threads; output fp32 scalar
__global__ void finish_kernel(const u32* __restrict__ part, float* __restrict__ out) {
  float v = 0.f;
  for (int i = threadIdx.x; i < NPIX; i += 1024) {
    v += 1.0f - dec_f32(part[i]);
  }
#pragma unroll
  for (int off = 32; off > 0; off >>= 1) v += __shfl_down(v, off);
  __shared__ float red[16];
  int w = threadIdx.x >> 6;
  if ((threadIdx.x & 63) == 0) red[w] = v;
  __syncthreads();
  if (threadIdx.x == 0) {
    float s = 0.f;
#pragma unroll
    for (int k = 0; k < 16; ++k) s += red[k];
    out[0] = s * (1.0f / (float)NPIX);
  }
}

// ---------------------------------------------------------------- launcher
extern "C" void kernel_launch(void* const* d_in, const int* in_sizes, int n_in,
                              void* d_out, int out_size, void* d_ws, size_t ws_size,
                              hipStream_t stream) {
  const float* x = (const float*)d_in[0];
  const float* s = (const float*)d_in[1];
  char* ws = (char*)d_ws;
  // layout (bytes):
  float* pa   = (float*)(ws + 0);         //   401408
  float* pb   = (float*)(ws + 401408);    //   401408
  float* ra   = (float*)(ws + 802816);    //    50176
  float* rb   = (float*)(ws + 852992);    //    50176
  u32*   part = (u32*)  (ws + 903168);    //    50176 (encoded row maxima)
  u16*   Ar   = (u16*)  (ws + 953344);    // 19267584
  u16*   Br   = (u16*)  (ws + 20220928);  // 19267584  -> total 39488512 B

  colsumsq_kernel<<<dim3(49, 8), 256, 0, stream>>>(x, s, pa, pb);
  rnorm_kernel<<<49, 256, 0, stream>>>(pa, pb, ra, rb, part);
  transpose_kernel<<<dim3(392, 24, 2), 256, 0, stream>>>(x, s, ra, rb, Ar, Br);
  gemm_max_kernel<<<dim3(8, 7, 49), 512, 0, stream>>>(Ar, Br, part);
  finish_kernel<<<1, 1024, 0, stream>>>(part, (float*)d_out);
}

// Round 4
// 457.571 us; speedup vs baseline: 1.0430x; 1.0039x over previous
//
#include <hip/hip_runtime.h>
#include <hip/hip_bf16.h>

typedef unsigned short u16;
typedef unsigned int u32;
typedef __attribute__((ext_vector_type(8))) short short8;
typedef __attribute__((ext_vector_type(4))) float floatx4;

#define NPIX 12544   // 112*112 = 49 * 256
#define KDIM 768     // channels = 12 * 64
#define EPSF 1e-8f
#define NT 12        // K tiles of 64
#define NTILE 49     // 12544 / 256

// ---------------------------------------------------------------- async G->LDS
__device__ __forceinline__ void gload_lds16(const void* g, void* l) {
  __builtin_amdgcn_global_load_lds(
      (const __attribute__((address_space(1))) void*)g,
      (__attribute__((address_space(3))) void*)l, 16, 0, 0);
}

// sortable-uint encoding of float (monotone): max over enc == max over float
__device__ __forceinline__ u32 enc_f32(float f) {
  u32 u = __float_as_uint(f);
  return (u & 0x80000000u) ? ~u : (u | 0x80000000u);
}
__device__ __forceinline__ float dec_f32(u32 e) {
  u32 u = (e & 0x80000000u) ? (e & 0x7FFFFFFFu) : ~e;
  return __uint_as_float(u);
}

// ---------------------------------------------------------------- K1: column sum-of-squares partials
// grid (49, 8), block 256. pa/pb: [8][NPIX]
__global__ void colsumsq_kernel(const float* __restrict__ a, const float* __restrict__ b,
                                float* __restrict__ pa, float* __restrict__ pb) {
  int i = blockIdx.x * 256 + threadIdx.x;
  int c0 = blockIdx.y * 96;
  float sa = 0.f, sb = 0.f;
#pragma unroll 4
  for (int c = c0; c < c0 + 96; ++c) {
    float va = a[(size_t)c * NPIX + i];
    float vb = b[(size_t)c * NPIX + i];
    sa += va * va;
    sb += vb * vb;
  }
  pa[(size_t)blockIdx.y * NPIX + i] = sa;
  pb[(size_t)blockIdx.y * NPIX + i] = sb;
}

// ---------------------------------------------------------------- K2: 1/(sqrt(sum+eps)+eps) + zero the atomic-max buffer
// grid 49, block 256
__global__ void rnorm_kernel(const float* __restrict__ pa, const float* __restrict__ pb,
                             float* __restrict__ ra, float* __restrict__ rb,
                             u32* __restrict__ part) {
  int i = blockIdx.x * 256 + threadIdx.x;
  float sa = 0.f, sb = 0.f;
#pragma unroll
  for (int c = 0; c < 8; ++c) {
    sa += pa[(size_t)c * NPIX + i];
    sb += pb[(size_t)c * NPIX + i];
  }
  ra[i] = 1.f / (sqrtf(sa + EPSF) + EPSF);
  rb[i] = 1.f / (sqrtf(sb + EPSF) + EPSF);
  part[i] = 0u;  // encoded floor (< enc of any finite float)
}

// ---------------------------------------------------------------- K3: transpose + normalize + bf16 cast
// (C,N) f32 -> (N,C) bf16.  grid (392, 24, 2), block 256 (=32x8)
__global__ void transpose_kernel(const float* __restrict__ a, const float* __restrict__ b,
                                 const float* __restrict__ ra, const float* __restrict__ rb,
                                 u16* __restrict__ Ar, u16* __restrict__ Br) {
  const float* src = blockIdx.z ? b : a;
  const float* rn  = blockIdx.z ? rb : ra;
  u16* dst         = blockIdx.z ? Br : Ar;
  __shared__ float tile[32][33];
  int i0 = blockIdx.x * 32;
  int c0 = blockIdx.y * 32;
  int tx = threadIdx.x & 31;
  int ty = threadIdx.x >> 5;  // 0..7
#pragma unroll
  for (int d = 0; d < 4; ++d) {
    int c = c0 + ty + d * 8;
    tile[ty + d * 8][tx] = src[(size_t)c * NPIX + i0 + tx];
  }
  __syncthreads();
#pragma unroll
  for (int d = 0; d < 4; ++d) {
    int il = ty + d * 8;
    int gi = i0 + il;
    float v = tile[tx][il] * rn[gi];
    __hip_bfloat16 h = __float2bfloat16(v);
    dst[(size_t)gi * KDIM + c0 + tx] = *reinterpret_cast<u16*>(&h);
  }
}

// ---------------------------------------------------------------- K4: 256x256 tile, 8 waves, BK=64,
// FREE-SCHEDULED K-tile body (compiler-pipelined ds_read/MFMA, one barrier per tile).
// Round-4 change: removed the 4-phase lockstep (per-phase barriers + lgkmcnt(0) +
// sched_barrier(0)) that alternated {all waves LDS-read} <-> {all waves MFMA}, idling
// each pipe ~50% and costing ~4000 cyc/K-tile of sync overhead. Now each K-tile is
// straight-line: issue 8 staging gloads (next tile, other buffer), then 24 ds_read_b128
// + 64 MFMA with compiler-inserted fine-grained lgkmcnt (m97-proven), then
// vmcnt(0)+__syncthreads once. Correctness: the single barrier orders all waves'
// reads-of-buf before next iteration's staging-into-buf, and vmcnt(0) ensures buf^1
// staging landed before the barrier releases readers; barriers fence LDS ops, so the
// compiler cannot hoist next-tile ds_reads above it.
// Dispatch (proven 2-D XCD scheme): grid (8, 7, 49). x = XCD (linear%8 round-robins XCDs),
// y = col tile within the XCD's chunk (XCD0: 7 tiles, XCD1-7: 6; dead y exits early),
// z = row tile SLOWEST -> A panel shared chip-wide per z-wave; B chunk (2.3-2.7 MB)
// pinned in the owning XCD's L2 (round-3: FETCH 485->161 MB, keep).
// LDS: A,B double-buffered = 2buf x 2half x 128x64 bf16 x {A,B} = 128 KiB (1 block/CU).
// Per wave (wm=wid>>2, wn=wid&3): output 128 rows x 64 cols = acc[8][4] 16x16 frags.
// LDS swizzle: row r, logical 16B-chunk c stored at slot (c + r) & 7; global source is
// pre-swizzled so global_load_lds dest stays linear (both-sides-or-neither).
__global__ __launch_bounds__(512, 2) void gemm_max_kernel(const u16* __restrict__ Ar,
                                                          const u16* __restrict__ Br,
                                                          u32* __restrict__ part) {
  const int x = blockIdx.x;                 // XCD chunk (linear%8 == x)
  const int y = blockIdx.y;                 // col tile within chunk
  const int live = (x == 0) ? 7 : 6;
  if (y >= live) return;                    // dead padding block (exits before any barrier)
  const int ct = (x == 0) ? y : 7 + (x - 1) * 6 + y;
  const int rt = blockIdx.z;
  const int row_base = rt * 256;
  const int col_base = ct * 256;

  __shared__ alignas(16) u16 As[2][2][128 * 64];  // [buf][half][row*64 + slot*8]
  __shared__ alignas(16) u16 Bs[2][2][128 * 64];

  const int tid = threadIdx.x;
  const int lane = tid & 63;
  const int wid = tid >> 6;   // 0..7
  const int wm = wid >> 2;    // A half (0..1)
  const int wn = wid & 3;     // B quarter (0..3)
  const int l15 = lane & 15;
  const int quad = lane >> 4;
  const int rb0 = (wn & 1) * 64;  // B row base within half (wn>>1)

  // staging: thread covers (row tid>>3 [+64], slot tid&7). Source chunk pre-swizzled:
  // LDS (row r, slot s) must hold logical chunk (s - r) & 7  (64 = 0 mod 8, so same for j=1)
  const int srow = tid >> 3;
  const int clog = ((tid & 7) - srow) & 7;
  const u16* gA = Ar + (size_t)(row_base + srow) * KDIM + clog * 8;
  const u16* gB = Br + (size_t)(col_base + srow) * KDIM + clog * 8;

  auto stageA = [&](int buf, int h, int t) {
    const u16* g = gA + (size_t)(h * 128) * KDIM + t * 64;
    gload_lds16(g, &As[buf][h][tid * 8]);
    gload_lds16(g + (size_t)64 * KDIM, &As[buf][h][4096 + tid * 8]);
  };
  auto stageB = [&](int buf, int h, int t) {
    const u16* g = gB + (size_t)(h * 128) * KDIM + t * 64;
    gload_lds16(g, &Bs[buf][h][tid * 8]);
    gload_lds16(g + (size_t)64 * KDIM, &Bs[buf][h][4096 + tid * 8]);
  };
  // frag read address (elements): row-major 64/row, slot rotated by row
  auto swz = [&](int row, int kk) {
    return row * 64 + ((((kk << 2) + quad + row) & 7) << 3);
  };

  floatx4 acc[8][4];
#pragma unroll
  for (int m = 0; m < 8; ++m)
#pragma unroll
    for (int n = 0; n < 4; ++n) acc[m][n] = (floatx4){0.f, 0.f, 0.f, 0.f};

  // prologue: tile 0 into buf 0
  stageA(0, 0, 0); stageA(0, 1, 0); stageB(0, 0, 0); stageB(0, 1, 0);
  asm volatile("s_waitcnt vmcnt(0)" ::: "memory");
  __builtin_amdgcn_s_barrier();

  for (int t = 0; t < NT; ++t) {
    const int buf = t & 1;
    const u16* pA = &As[buf][wm][0];
    const u16* pB = &Bs[buf][wn >> 1][0];

    // issue next-tile staging first: ~full K-tile of cover before the vmcnt(0) drain
    if (t + 1 < NT) {
      stageA(buf ^ 1, 0, t + 1); stageA(buf ^ 1, 1, t + 1);
      stageB(buf ^ 1, 0, t + 1); stageB(buf ^ 1, 1, t + 1);
    }

    // two K=32 halves; 12 frags live at a time, compiler pipelines reads vs MFMA
#pragma unroll
    for (int kk = 0; kk < 2; ++kk) {
      short8 a_frag[8], b_frag[4];
#pragma unroll
      for (int mm = 0; mm < 8; ++mm)
        a_frag[mm] = *(const short8*)&pA[swz(mm * 16 + l15, kk)];
#pragma unroll
      for (int n = 0; n < 4; ++n)
        b_frag[n] = *(const short8*)&pB[swz(rb0 + n * 16 + l15, kk)];
#pragma unroll
      for (int mm = 0; mm < 8; ++mm)
#pragma unroll
        for (int n = 0; n < 4; ++n)
          acc[mm][n] = __builtin_amdgcn_mfma_f32_16x16x32_bf16(a_frag[mm], b_frag[n], acc[mm][n], 0, 0, 0);
    }

    asm volatile("s_waitcnt vmcnt(0)" ::: "memory");  // buf^1 staging landed
    __syncthreads();                                  // all reads of buf done; full fence
  }

  // epilogue: per-row max over the 256-col tile.
  // C frag layout: col = l15 (+n*16), row = quad*4 + rr (+m*16, +wm*128)
  float* s_max = reinterpret_cast<float*>(&As[0][0][0]);  // [4][256], overlays As (done with LDS)
#pragma unroll
  for (int m = 0; m < 8; ++m) {
#pragma unroll
    for (int rr = 0; rr < 4; ++rr) {
      float best = fmaxf(fmaxf(acc[m][0][rr], acc[m][1][rr]),
                         fmaxf(acc[m][2][rr], acc[m][3][rr]));
      best = fmaxf(best, __shfl_xor(best, 1));
      best = fmaxf(best, __shfl_xor(best, 2));
      best = fmaxf(best, __shfl_xor(best, 4));
      best = fmaxf(best, __shfl_xor(best, 8));
      if (l15 == 0)
        s_max[wn * 256 + wm * 128 + m * 16 + quad * 4 + rr] = best;  // unique writer per entry
    }
  }
  __syncthreads();
  if (tid < 256) {
    float mx = fmaxf(fmaxf(s_max[tid], s_max[256 + tid]),
                     fmaxf(s_max[512 + tid], s_max[768 + tid]));
    atomicMax(&part[row_base + tid], enc_f32(mx));
  }
}

// ---------------------------------------------------------------- K5: decode + loss
// single block, 1024 threads; output fp32 scalar
__global__ void finish_kernel(const u32* __restrict__ part, float* __restrict__ out) {
  float v = 0.f;
  for (int i = threadIdx.x; i < NPIX; i += 1024) {
    v += 1.0f - dec_f32(part[i]);
  }
#pragma unroll
  for (int off = 32; off > 0; off >>= 1) v += __shfl_down(v, off);
  __shared__ float red[16];
  int w = threadIdx.x >> 6;
  if ((threadIdx.x & 63) == 0) red[w] = v;
  __syncthreads();
  if (threadIdx.x == 0) {
    float s = 0.f;
#pragma unroll
    for (int k = 0; k < 16; ++k) s += red[k];
    out[0] = s * (1.0f / (float)NPIX);
  }
}

// ---------------------------------------------------------------- launcher
extern "C" void kernel_launch(void* const* d_in, const int* in_sizes, int n_in,
                              void* d_out, int out_size, void* d_ws, size_t ws_size,
                              hipStream_t stream) {
  const float* x = (const float*)d_in[0];
  const float* s = (const float*)d_in[1];
  char* ws = (char*)d_ws;
  // layout (bytes):
  float* pa   = (float*)(ws + 0);         //   401408
  float* pb   = (float*)(ws + 401408);    //   401408
  float* ra   = (float*)(ws + 802816);    //    50176
  float* rb   = (float*)(ws + 852992);    //    50176
  u32*   part = (u32*)  (ws + 903168);    //    50176 (encoded row maxima)
  u16*   Ar   = (u16*)  (ws + 953344);    // 19267584
  u16*   Br   = (u16*)  (ws + 20220928);  // 19267584  -> total 39488512 B

  colsumsq_kernel<<<dim3(49, 8), 256, 0, stream>>>(x, s, pa, pb);
  rnorm_kernel<<<49, 256, 0, stream>>>(pa, pb, ra, rb, part);
  transpose_kernel<<<dim3(392, 24, 2), 256, 0, stream>>>(x, s, ra, rb, Ar, Br);
  gemm_max_kernel<<<dim3(8, 7, 49), 512, 0, stream>>>(Ar, Br, part);
  finish_kernel<<<1, 1024, 0, stream>>>(part, (float*)d_out);
}

// Round 5
// 404.234 us; speedup vs baseline: 1.1806x; 1.1319x over previous
//
#include <hip/hip_runtime.h>
#include <hip/hip_bf16.h>

typedef unsigned short u16;
typedef unsigned int u32;
typedef __attribute__((ext_vector_type(8))) short short8;
typedef __attribute__((ext_vector_type(4))) float floatx4;

#define NPIX 12544   // 112*112 = 49 * 256
#define KDIM 768     // channels = 24 * 32
#define EPSF 1e-8f
#define NCH 24       // K chunks of 32
#define NTILE 49     // 12544 / 256

// ---------------------------------------------------------------- async G->LDS
__device__ __forceinline__ void gload_lds16(const void* g, void* l) {
  __builtin_amdgcn_global_load_lds(
      (const __attribute__((address_space(1))) void*)g,
      (__attribute__((address_space(3))) void*)l, 16, 0, 0);
}

// sortable-uint encoding of float (monotone): max over enc == max over float
__device__ __forceinline__ u32 enc_f32(float f) {
  u32 u = __float_as_uint(f);
  return (u & 0x80000000u) ? ~u : (u | 0x80000000u);
}
__device__ __forceinline__ float dec_f32(u32 e) {
  u32 u = (e & 0x80000000u) ? (e & 0x7FFFFFFFu) : ~e;
  return __uint_as_float(u);
}

// ---------------------------------------------------------------- K1: column sum-of-squares partials
// grid (49, 8), block 256. pa/pb: [8][NPIX]
__global__ void colsumsq_kernel(const float* __restrict__ a, const float* __restrict__ b,
                                float* __restrict__ pa, float* __restrict__ pb) {
  int i = blockIdx.x * 256 + threadIdx.x;
  int c0 = blockIdx.y * 96;
  float sa = 0.f, sb = 0.f;
#pragma unroll 4
  for (int c = c0; c < c0 + 96; ++c) {
    float va = a[(size_t)c * NPIX + i];
    float vb = b[(size_t)c * NPIX + i];
    sa += va * va;
    sb += vb * vb;
  }
  pa[(size_t)blockIdx.y * NPIX + i] = sa;
  pb[(size_t)blockIdx.y * NPIX + i] = sb;
}

// ---------------------------------------------------------------- K2: 1/(sqrt(sum+eps)+eps) + zero the atomic-max buffer
// grid 49, block 256
__global__ void rnorm_kernel(const float* __restrict__ pa, const float* __restrict__ pb,
                             float* __restrict__ ra, float* __restrict__ rb,
                             u32* __restrict__ part) {
  int i = blockIdx.x * 256 + threadIdx.x;
  float sa = 0.f, sb = 0.f;
#pragma unroll
  for (int c = 0; c < 8; ++c) {
    sa += pa[(size_t)c * NPIX + i];
    sb += pb[(size_t)c * NPIX + i];
  }
  ra[i] = 1.f / (sqrtf(sa + EPSF) + EPSF);
  rb[i] = 1.f / (sqrtf(sb + EPSF) + EPSF);
  part[i] = 0u;  // encoded floor (< enc of any finite float)
}

// ---------------------------------------------------------------- K3: transpose + normalize + bf16 cast
// (C,N) f32 -> (N,C) bf16.  grid (392, 24, 2), block 256 (=32x8)
__global__ void transpose_kernel(const float* __restrict__ a, const float* __restrict__ b,
                                 const float* __restrict__ ra, const float* __restrict__ rb,
                                 u16* __restrict__ Ar, u16* __restrict__ Br) {
  const float* src = blockIdx.z ? b : a;
  const float* rn  = blockIdx.z ? rb : ra;
  u16* dst         = blockIdx.z ? Br : Ar;
  __shared__ float tile[32][33];
  int i0 = blockIdx.x * 32;
  int c0 = blockIdx.y * 32;
  int tx = threadIdx.x & 31;
  int ty = threadIdx.x >> 5;  // 0..7
#pragma unroll
  for (int d = 0; d < 4; ++d) {
    int c = c0 + ty + d * 8;
    tile[ty + d * 8][tx] = src[(size_t)c * NPIX + i0 + tx];
  }
  __syncthreads();
#pragma unroll
  for (int d = 0; d < 4; ++d) {
    int il = ty + d * 8;
    int gi = i0 + il;
    float v = tile[tx][il] * rn[gi];
    __hip_bfloat16 h = __float2bfloat16(v);
    dst[(size_t)gi * KDIM + c0 + tx] = *reinterpret_cast<u16*>(&h);
  }
}

// ---------------------------------------------------------------- K4: 256x256 tile, 8 waves,
// COUNTED-VMCNT 4-slot ring pipeline (the T4 ingredient rounds 2-4 lacked).
// Evidence: rounds 2/3/4 (4-phase lockstep, free-schedule) all pinned at 28-30% MfmaUtil —
// the shared invariant was s_waitcnt vmcnt(0) once per K-tile (m218: drain0 == 1-phase).
// New structure: K split into 24 chunks of BK=32. LDS = 4 ring slots per matrix
// (slot = chunk&3, 256x32 bf16 = 16 KB each; A 64 KB + B 64 KB = 128 KiB, 1 block/CU).
// Chunk c body:
//   phi1: ds_read A(m0-7 half1: 4) + B (4) [chunk c, landed]; issue 4 gload_lds for c+3;
//         16 MFMA (compiler-scheduled waits; no barrier between reads and MFMA -> waves drift,
//         LDS-read overlaps MFMA across waves)
//   phi2: ds_read A(m4-7: 4); s_waitcnt vmcnt(8)  <- COUNTED: c+2,c+3 (8 loads) stay in flight;
//         barrier (all waves agree c+1 landed); lgkmcnt(0); 16 MFMA; barrier (all reads of c
//         done -> slot c&3 reusable for c+4 next chunk)
// Ring safety: stages for c+3 (issued phi1 of c) target slot (c+3)&3=(c-1)&3 whose readers
// finished at c-1's end barrier (lgkmcnt(0) precedes it, so reads have executed). Waits are
// per-wave; the barrier after each wave's vmcnt makes the guarantee block-wide.
// Tail: c=21 -> vmcnt(4), c=22 -> vmcnt(0), c=23 -> no wait. Never drains mid-loop.
// LDS swizzle (BK=32, 4 slots/row): slot = ((row>>1) + kquad)&3; each 16-lane read phase
// covers all 32 banks exactly 2x (conflict-free). Global source pre-swizzled, LDS dest linear.
// Dispatch (round-3 proven): grid (8,7,49), x=XCD, y=col tile in chunk, z=row tile slowest.
__global__ __launch_bounds__(512, 2) void gemm_max_kernel(const u16* __restrict__ Ar,
                                                          const u16* __restrict__ Br,
                                                          u32* __restrict__ part) {
  const int x = blockIdx.x;                 // XCD chunk (linear%8 == x)
  const int y = blockIdx.y;                 // col tile within chunk
  const int live = (x == 0) ? 7 : 6;
  if (y >= live) return;                    // dead padding block (exits before any barrier)
  const int ct = (x == 0) ? y : 7 + (x - 1) * 6 + y;
  const int rt = blockIdx.z;
  const int row_base = rt * 256;
  const int col_base = ct * 256;

  __shared__ alignas(16) u16 As[4 * 8192];  // 4 ring slots: [256 rows][4 slots][8 elems]
  __shared__ alignas(16) u16 Bs[4 * 8192];

  const int tid = threadIdx.x;
  const int lane = tid & 63;
  const int wid = tid >> 6;   // 0..7
  const int wm = wid >> 2;    // A half (0..1)
  const int wn = wid & 3;     // B quarter (0..3)
  const int l15 = lane & 15;
  const int quad = lane >> 4;

  // staging: thread covers rows (tid>>2) and (tid>>2)+128, 16B slot tid&3.
  // LDS (row r, slot s) holds logical k-group (s - (r>>1)) & 3  (pre-swizzled source;
  // row+128 shifts r>>1 by 64 = 0 mod 4, so same k-group for both rows)
  const int srow = tid >> 2;                       // 0..127
  const int clog = ((tid & 3) - (srow >> 1)) & 3;  // logical 8-elem k-group
  const u16* gAt = Ar + (size_t)(row_base + srow) * KDIM + clog * 8;
  const u16* gBt = Br + (size_t)(col_base + srow) * KDIM + clog * 8;
  u16* lA = &As[tid * 8];  // dest linear in tid: (tid>>2)*128 + (tid&3)*8... = tid*8 elems
  u16* lB = &Bs[tid * 8];

#define STAGE4(T)                                                              \
  do {                                                                         \
    gload_lds16(gAt + (T) * 32,              lA + (((T) & 3) << 13));          \
    gload_lds16(gAt + (T) * 32 + 128 * KDIM, lA + (((T) & 3) << 13) + 4096);   \
    gload_lds16(gBt + (T) * 32,              lB + (((T) & 3) << 13));          \
    gload_lds16(gBt + (T) * 32 + 128 * KDIM, lB + (((T) & 3) << 13) + 4096);   \
  } while (0)

  // frag element offsets within a slot: row R, k-quad quad -> R*32 + (((R>>1)+quad)&3)*8
  int aoff[8], boff[4];
#pragma unroll
  for (int mm = 0; mm < 8; ++mm) {
    int R = wm * 128 + mm * 16 + l15;
    aoff[mm] = R * 32 + ((((R >> 1) + quad) & 3) << 3);
  }
#pragma unroll
  for (int nf = 0; nf < 4; ++nf) {
    int Cc = wn * 64 + nf * 16 + l15;
    boff[nf] = Cc * 32 + ((((Cc >> 1) + quad) & 3) << 3);
  }

  floatx4 acc[8][4];
#pragma unroll
  for (int m = 0; m < 8; ++m)
#pragma unroll
    for (int n = 0; n < 4; ++n) acc[m][n] = (floatx4){0.f, 0.f, 0.f, 0.f};

  // prologue: stage chunks 0,1,2; wait chunk 0 landed (1,2 stay in flight)
  STAGE4(0); STAGE4(1); STAGE4(2);
  asm volatile("s_waitcnt vmcnt(8)" ::: "memory");
  __builtin_amdgcn_s_barrier();

#define CHUNK(C, VMSTR, DOSTG, DOWAIT)                                                        \
  do {                                                                                        \
    const u16* pAs = &As[((C) & 3) << 13];                                                    \
    const u16* pBs = &Bs[((C) & 3) << 13];                                                    \
    short8 af[4], bf[4], af2[4];                                                              \
    _Pragma("unroll") for (int mm = 0; mm < 4; ++mm)                                          \
        af[mm] = *(const short8*)&pAs[aoff[mm]];                                              \
    _Pragma("unroll") for (int nf = 0; nf < 4; ++nf)                                          \
        bf[nf] = *(const short8*)&pBs[boff[nf]];                                              \
    if (DOSTG) STAGE4((C) + 3);                                                               \
    __builtin_amdgcn_s_setprio(1);                                                            \
    _Pragma("unroll") for (int mm = 0; mm < 4; ++mm)                                          \
      _Pragma("unroll") for (int nf = 0; nf < 4; ++nf)                                        \
          acc[mm][nf] = __builtin_amdgcn_mfma_f32_16x16x32_bf16(af[mm], bf[nf],               \
                                                                acc[mm][nf], 0, 0, 0);        \
    __builtin_amdgcn_s_setprio(0);                                                            \
    _Pragma("unroll") for (int mm = 0; mm < 4; ++mm)                                          \
        af2[mm] = *(const short8*)&pAs[aoff[mm + 4]];                                         \
    if (DOWAIT) { asm volatile("s_waitcnt " VMSTR ::: "memory"); }                            \
    __builtin_amdgcn_sched_barrier(0);                                                        \
    __builtin_amdgcn_s_barrier();             /* all waves: chunk C+1 landed */               \
    asm volatile("s_waitcnt lgkmcnt(0)" ::: "memory");                                        \
    __builtin_amdgcn_sched_barrier(0);                                                        \
    __builtin_amdgcn_s_setprio(1);                                                            \
    _Pragma("unroll") for (int mm = 0; mm < 4; ++mm)                                          \
      _Pragma("unroll") for (int nf = 0; nf < 4; ++nf)                                        \
          acc[mm + 4][nf] = __builtin_amdgcn_mfma_f32_16x16x32_bf16(af2[mm], bf[nf],          \
                                                                    acc[mm + 4][nf], 0, 0, 0);\
    __builtin_amdgcn_s_setprio(0);                                                            \
    __builtin_amdgcn_s_barrier();             /* reads of C done -> slot reusable */          \
  } while (0)

  CHUNK(0,  "vmcnt(8)", 1, 1);  CHUNK(1,  "vmcnt(8)", 1, 1);
  CHUNK(2,  "vmcnt(8)", 1, 1);  CHUNK(3,  "vmcnt(8)", 1, 1);
  CHUNK(4,  "vmcnt(8)", 1, 1);  CHUNK(5,  "vmcnt(8)", 1, 1);
  CHUNK(6,  "vmcnt(8)", 1, 1);  CHUNK(7,  "vmcnt(8)", 1, 1);
  CHUNK(8,  "vmcnt(8)", 1, 1);  CHUNK(9,  "vmcnt(8)", 1, 1);
  CHUNK(10, "vmcnt(8)", 1, 1);  CHUNK(11, "vmcnt(8)", 1, 1);
  CHUNK(12, "vmcnt(8)", 1, 1);  CHUNK(13, "vmcnt(8)", 1, 1);
  CHUNK(14, "vmcnt(8)", 1, 1);  CHUNK(15, "vmcnt(8)", 1, 1);
  CHUNK(16, "vmcnt(8)", 1, 1);  CHUNK(17, "vmcnt(8)", 1, 1);
  CHUNK(18, "vmcnt(8)", 1, 1);  CHUNK(19, "vmcnt(8)", 1, 1);
  CHUNK(20, "vmcnt(8)", 1, 1);
  CHUNK(21, "vmcnt(4)", 0, 1);
  CHUNK(22, "vmcnt(0)", 0, 1);
  CHUNK(23, "vmcnt(0)", 0, 0);

#undef CHUNK
#undef STAGE4

  // epilogue: per-row max over the 256-col tile.
  // C frag layout: col = l15 (+n*16), row = quad*4 + rr (+m*16, +wm*128)
  float* s_max = reinterpret_cast<float*>(&As[0]);  // [4][256], overlays As (done with LDS)
#pragma unroll
  for (int m = 0; m < 8; ++m) {
#pragma unroll
    for (int rr = 0; rr < 4; ++rr) {
      float best = fmaxf(fmaxf(acc[m][0][rr], acc[m][1][rr]),
                         fmaxf(acc[m][2][rr], acc[m][3][rr]));
      best = fmaxf(best, __shfl_xor(best, 1));
      best = fmaxf(best, __shfl_xor(best, 2));
      best = fmaxf(best, __shfl_xor(best, 4));
      best = fmaxf(best, __shfl_xor(best, 8));
      if (l15 == 0)
        s_max[wn * 256 + wm * 128 + m * 16 + quad * 4 + rr] = best;  // unique writer per entry
    }
  }
  __syncthreads();
  if (tid < 256) {
    float mx = fmaxf(fmaxf(s_max[tid], s_max[256 + tid]),
                     fmaxf(s_max[512 + tid], s_max[768 + tid]));
    atomicMax(&part[row_base + tid], enc_f32(mx));
  }
}

// ---------------------------------------------------------------- K5: decode + loss
// single block, 1024 threads; output fp32 scalar
__global__ void finish_kernel(const u32* __restrict__ part, float* __restrict__ out) {
  float v = 0.f;
  for (int i = threadIdx.x; i < NPIX; i += 1024) {
    v += 1.0f - dec_f32(part[i]);
  }
#pragma unroll
  for (int off = 32; off > 0; off >>= 1) v += __shfl_down(v, off);
  __shared__ float red[16];
  int w = threadIdx.x >> 6;
  if ((threadIdx.x & 63) == 0) red[w] = v;
  __syncthreads();
  if (threadIdx.x == 0) {
    float s = 0.f;
#pragma unroll
    for (int k = 0; k < 16; ++k) s += red[k];
    out[0] = s * (1.0f / (float)NPIX);
  }
}

// ---------------------------------------------------------------- launcher
extern "C" void kernel_launch(void* const* d_in, const int* in_sizes, int n_in,
                              void* d_out, int out_size, void* d_ws, size_t ws_size,
                              hipStream_t stream) {
  const float* x = (const float*)d_in[0];
  const float* s = (const float*)d_in[1];
  char* ws = (char*)d_ws;
  // layout (bytes):
  float* pa   = (float*)(ws + 0);         //   401408
  float* pb   = (float*)(ws + 401408);    //   401408
  float* ra   = (float*)(ws + 802816);    //    50176
  float* rb   = (float*)(ws + 852992);    //    50176
  u32*   part = (u32*)  (ws + 903168);    //    50176 (encoded row maxima)
  u16*   Ar   = (u16*)  (ws + 953344);    // 19267584
  u16*   Br   = (u16*)  (ws + 20220928);  // 19267584  -> total 39488512 B

  colsumsq_kernel<<<dim3(49, 8), 256, 0, stream>>>(x, s, pa, pb);
  rnorm_kernel<<<49, 256, 0, stream>>>(pa, pb, ra, rb, part);
  transpose_kernel<<<dim3(392, 24, 2), 256, 0, stream>>>(x, s, ra, rb, Ar, Br);
  gemm_max_kernel<<<dim3(8, 7, 49), 512, 0, stream>>>(Ar, Br, part);
  finish_kernel<<<1, 1024, 0, stream>>>(part, (float*)d_out);
}